// Round 14
// baseline (64.906 us; speedup 1.0000x reference)
//
#include <hip/hip_runtime.h>

#define VOCABN 256
#define DN 512
#define DSN 2
#define KN 5
#define BN 8
#define LN 8192
#define WN 12                     // window positions per block (multiple of lcm(2,3,4)=12)
#define NW12 ((LN + WN - 1) / WN) // 683 windows per batch
#define LOUTN (LN / DSN)          // 4096
#define NROWS (KN * VOCABN)       // 1280 G rows
#define ROWB (DN * 2)             // 1024 bytes per bf16 G row
#define KPLANE (VOCABN * ROWB)    // 262144 bytes per k-plane
#define ZOFFB (NROWS * ROWB)      // invalid-tap base: rows 1280+q*256 are zero rows
#define SBIAS_IDX (NROWS + 4 * VOCABN + 1)  // 2305
#define ISP 4                     // split over i: 4 chunks of 128

// Workspace layout (BYTES) — derived:
//   Gp : ISP*NROWS*DN*4 = 10,485,760 @ 0
//   G  : 2305*ROWB      =  2,360,320 @ 10,485,760
//   SW : 2306*4         =      9,224 @ 12,846,080
#define GP_BYTES ((size_t)ISP * NROWS * DN * 4)
#define G_OFF GP_BYTES
#define SW_OFF (G_OFF + (size_t)2305 * ROWB)

typedef float nf4 __attribute__((ext_vector_type(4)));  // clang vector for nontemporal store

__device__ inline unsigned short f2bf(float f) {  // RNE f32->bf16
  unsigned int x = __float_as_uint(f);
  return (unsigned short)((x + 0x7FFFu + ((x >> 16) & 1u)) >> 16);
}

// ---------------- kernel 1: build GEMM partials (round-7/11 verbatim) ----------------
// Gp[isp][k*256+v][o] = sum_{i in [isp*128, isp*128+128)} emb[v][i] * cw[o][i][k]
// grid 640 = 4vt x 8ot x (5k x 4isp); 256 thr; 4v x 4o per thread; 4 stages of 32 i.
__global__ __launch_bounds__(256) void gbuild_kernel(const float* __restrict__ emb,
                                                     const float* __restrict__ cw,
                                                     float* __restrict__ Gp) {
  const int bx = blockIdx.x;
  const int vt = bx & 3, ot = (bx >> 2) & 7;
  const int kq = bx >> 5;
  const int k = kq % 5, isp = kq / 5;
  const int v0 = vt * 64, o0 = ot * 64;
  const int tid = threadIdx.x;
  const int ox = tid & 15, vx = tid >> 4;
  const int c = tid & 31, rr = tid >> 5;  // stage: i-col 0..31, row-group 0..7
  __shared__ float se[32][68];  // [i][v]
  __shared__ float wt[32][68];  // [i][o]
  float acc[4][4] = {};
  for (int ic = 0; ic < 4; ++ic) {
    const int i0 = isp * 128 + ic * 32;
    __syncthreads();  // protect previous iter's reads
#pragma unroll
    for (int p = 0; p < 8; ++p) {
      const int q = p * 8 + rr;
      se[c][q] = emb[(size_t)(v0 + q) * DN + i0 + c];                  // coalesced rows
      wt[c][q] = cw[((size_t)(o0 + q) * DN + i0 + c) * KN + k];        // strided, L2-hot
    }
    __syncthreads();
#pragma unroll
    for (int i = 0; i < 32; ++i) {
      const float4 a = *(const float4*)&se[i][vx * 4];
      const float4 b = *(const float4*)&wt[i][ox * 4];
      acc[0][0] += a.x * b.x; acc[0][1] += a.x * b.y; acc[0][2] += a.x * b.z; acc[0][3] += a.x * b.w;
      acc[1][0] += a.y * b.x; acc[1][1] += a.y * b.y; acc[1][2] += a.y * b.z; acc[1][3] += a.y * b.w;
      acc[2][0] += a.z * b.x; acc[2][1] += a.z * b.y; acc[2][2] += a.z * b.z; acc[2][3] += a.z * b.w;
      acc[3][0] += a.w * b.x; acc[3][1] += a.w * b.y; acc[3][2] += a.w * b.z; acc[3][3] += a.w * b.w;
    }
  }
#pragma unroll
  for (int vi = 0; vi < 4; ++vi) {
    const int row = k * VOCABN + v0 + vx * 4 + vi;
    float4 f;
    f.x = acc[vi][0];
    f.y = acc[vi][1];
    f.z = acc[vi][2];
    f.w = acc[vi][3];
    *(float4*)(Gp + ((size_t)isp * NROWS + row) * DN + o0 + ox * 4) = f;
  }
}

// ---------------- kernel 2: merged reduce + score table (round-11 verbatim) ----------------
__global__ __launch_bounds__(256) void gswr_kernel(const float* __restrict__ Gp,
                                                   const float* __restrict__ conv_b,
                                                   const float* __restrict__ score_w,
                                                   unsigned int* __restrict__ G32,
                                                   float* __restrict__ SW) {
  const int r = blockIdx.x;
  const int tid = threadIdx.x;
  __shared__ float sred[4];
  if (r >= NROWS && r < NROWS + 5) {  // zero rows
    const int z = NROWS + (r - NROWS) * VOCABN;
    G32[(size_t)z * 256 + tid] = 0u;
    if (tid == 0) SW[z] = 0.f;
    return;
  }
  const float2 sw2 = *(const float2*)(score_w + tid * 2);
  float sdot;
  if (r == NROWS + 5) {  // sbias = conv_b . score_w
    const float2 cb2 = *(const float2*)(conv_b + tid * 2);
    sdot = cb2.x * sw2.x + cb2.y * sw2.y;
  } else {
    float x = 0.f, y = 0.f;
#pragma unroll
    for (int isp = 0; isp < ISP; ++isp) {
      const float2 p = *(const float2*)(Gp + ((size_t)isp * NROWS + r) * DN + tid * 2);
      x += p.x;
      y += p.y;
    }
    G32[(size_t)r * 256 + tid] = (unsigned)f2bf(x) | ((unsigned)f2bf(y) << 16);
    sdot = x * sw2.x + y * sw2.y;
  }
#pragma unroll
  for (int off = 32; off > 0; off >>= 1) sdot += __shfl_xor(sdot, off, 64);
  if ((tid & 63) == 0) sred[tid >> 6] = sdot;
  __syncthreads();
  if (tid == 0) {
    const float v = sred[0] + sred[1] + sred[2] + sred[3];
    if (r == NROWS + 5) SW[SBIAS_IDX] = v;
    else SW[r] = v;
  }
}

// ---------------- kernel 3: fused GBST main (128 thr, 4 ch/thread, uint2 gathers) --------
// block = (batch, 12-position window), 128 threads; thread t owns channels [4t,4t+4).
// Gathers: uint2 (4 bf16) per tap -> half the wave requests of round-11.
// Pool sums recomputed in epilogue (no S-register arrays): state = y[12] float4.
__global__ __launch_bounds__(128, 4) void gbst_main_kernel(const int* __restrict__ ids,
                                                           const unsigned short* __restrict__ G,
                                                           const float* __restrict__ SW,
                                                           const float* __restrict__ conv_b,
                                                           float* __restrict__ out) {
  const int blk = blockIdx.x;
  const int b = blk / NW12;
  const int w = blk % NW12;
  const int l0 = w * WN;
  const int tid = threadIdx.x;

  __shared__ float t_s[WN];
  __shared__ float4 wm_s[WN];

  // P0: block-uniform tap byte-offsets (scalar path)
  int joff[WN + 4];
#pragma unroll
  for (int j = 0; j < WN + 4; ++j) {
    const int p = l0 + j - 2;
    const bool v = ((unsigned)p < (unsigned)LN);
    const int a = v ? (b * LN + p) : 0;
    const int id = ids[a];
    joff[j] = v ? (id * ROWB) : ZOFFB;
  }

  // P1: gathers — uint2 = 4 bf16 channels; scalar base + t*8 voffset
  const char* Gc = (const char*)G;
  float4 y[WN];
#pragma unroll
  for (int s = 0; s < WN; ++s) {
    float a0 = 0.f, a1 = 0.f, a2 = 0.f, a3 = 0.f;
#pragma unroll
    for (int kk = 0; kk < KN; ++kk) {
      const uint2 g = ((const uint2*)(Gc + (joff[s + kk] + kk * KPLANE)))[tid];
      a0 += __uint_as_float(g.x << 16);
      a1 += __uint_as_float(g.x & 0xFFFF0000u);
      a2 += __uint_as_float(g.y << 16);
      a3 += __uint_as_float(g.y & 0xFFFF0000u);
    }
    y[s].x = a0; y[s].y = a1; y[s].z = a2; y[s].w = a3;
  }
  const float4 bias = *(const float4*)(conv_b + tid * 4);
#pragma unroll
  for (int s = 0; s < WN; ++s) {
    const bool valid = (l0 + s) < LN;  // block-uniform
    y[s].x = valid ? y[s].x + bias.x : 0.f;
    y[s].y = valid ? y[s].y + bias.y : 0.f;
    y[s].z = valid ? y[s].z + bias.z : 0.f;
    y[s].w = valid ? y[s].w + bias.w : 0.f;
  }

  // P2 (wave 0 only): scalar-loaded scores, then softmax
  if (tid < 64) {
    const float sbias = SW[SBIAS_IDX];
    float t[WN];
#pragma unroll
    for (int s = 0; s < WN; ++s) {
      float tv = sbias;
#pragma unroll
      for (int kk = 0; kk < KN; ++kk) tv += SW[(joff[s + kk] >> 10) + kk * VOCABN];
      t[s] = (l0 + s < LN) ? tv : 0.f;
    }
    if (tid == 0) {
#pragma unroll
      for (int s = 0; s < WN; ++s) t_s[s] = t[s];  // compile-time indices only
    }
    if (tid < WN && l0 + tid < LN) {
      const int ll = tid;
      float s1 = t_s[ll];
      int j2 = ll & ~1;
      float s2 = 0.5f * (t_s[j2] + t_s[j2 + 1]);
      int j3 = (ll / 3) * 3;
      float s3 = (1.f / 3.f) * (t_s[j3] + t_s[j3 + 1] + t_s[j3 + 2]);
      int j4 = ll & ~3;
      float s4 = 0.25f * (t_s[j4] + t_s[j4 + 1] + t_s[j4 + 2] + t_s[j4 + 3]);
      float mx = fmaxf(fmaxf(s1, s2), fmaxf(s3, s4));
      float e1 = __expf(s1 - mx), e2 = __expf(s2 - mx);
      float e3 = __expf(s3 - mx), e4 = __expf(s4 - mx);
      float inv = 1.f / (e1 + e2 + e3 + e4);
      wm_s[ll] = make_float4(e1 * inv, e2 * inv, e3 * inv, e4 * inv);
    }
  }
  __syncthreads();

  // P3: latent mix + final /2 downsample; pool sums recomputed per output row
#pragma unroll
  for (int jo = 0; jo < WN / 2; ++jo) {
    const int orow = (l0 >> 1) + jo;
    if (orow < LOUTN) {
      float a0 = 0.f, a1 = 0.f, a2 = 0.f, a3 = 0.f;
#pragma unroll
      for (int dl = 0; dl < 2; ++dl) {
        const int ll = 2 * jo + dl;
        const float4 wv = wm_s[ll];
        const int b2 = ll & ~1;          // pair base
        const int b3 = (ll / 3) * 3;     // triple base
        const int b4 = ll & ~3;          // quad base
        const float c1 = wv.x;
        const float c2 = wv.y * 0.5f;
        const float c3 = wv.z * (1.f / 3.f);
        const float c4 = wv.w * 0.25f;
        a0 += c1 * y[ll].x + c2 * (y[b2].x + y[b2 + 1].x) +
              c3 * (y[b3].x + y[b3 + 1].x + y[b3 + 2].x) +
              c4 * (y[b4].x + y[b4 + 1].x + y[b4 + 2].x + y[b4 + 3].x);
        a1 += c1 * y[ll].y + c2 * (y[b2].y + y[b2 + 1].y) +
              c3 * (y[b3].y + y[b3 + 1].y + y[b3 + 2].y) +
              c4 * (y[b4].y + y[b4 + 1].y + y[b4 + 2].y + y[b4 + 3].y);
        a2 += c1 * y[ll].z + c2 * (y[b2].z + y[b2 + 1].z) +
              c3 * (y[b3].z + y[b3 + 1].z + y[b3 + 2].z) +
              c4 * (y[b4].z + y[b4 + 1].z + y[b4 + 2].z + y[b4 + 3].z);
        a3 += c1 * y[ll].w + c2 * (y[b2].w + y[b2 + 1].w) +
              c3 * (y[b3].w + y[b3 + 1].w + y[b3 + 2].w) +
              c4 * (y[b4].w + y[b4 + 1].w + y[b4 + 2].w + y[b4 + 3].w);
      }
      nf4 o4;
      o4.x = 0.5f * a0;
      o4.y = 0.5f * a1;
      o4.z = 0.5f * a2;
      o4.w = 0.5f * a3;
      __builtin_nontemporal_store(o4, (nf4*)(out + ((size_t)b * LOUTN + orow) * DN + tid * 4));
    }
  }
}

extern "C" void kernel_launch(void* const* d_in, const int* in_sizes, int n_in,
                              void* d_out, int out_size, void* d_ws, size_t ws_size,
                              hipStream_t stream) {
  const int* ids = (const int*)d_in[0];
  const float* emb = (const float*)d_in[1];
  const float* conv_w = (const float*)d_in[2];
  const float* conv_b = (const float*)d_in[3];
  const float* score_w = (const float*)d_in[4];
  float* out = (float*)d_out;

  char* ws = (char*)d_ws;
  float* Gp = (float*)ws;                               // 10,485,760 B
  unsigned short* G = (unsigned short*)(ws + G_OFF);    // 2,360,320 B @ 10,485,760
  float* SW = (float*)(ws + SW_OFF);                    // 9,224 B @ 12,846,080

  gbuild_kernel<<<dim3(640), dim3(256), 0, stream>>>(emb, conv_w, Gp);
  gswr_kernel<<<dim3(NROWS + 6), dim3(256), 0, stream>>>(Gp, conv_b, score_w,
                                                         (unsigned int*)G, SW);
  gbst_main_kernel<<<dim3(BN * NW12), dim3(128), 0, stream>>>(ids, G, SW, conv_b, out);
}

// Round 15
// 51.713 us; speedup vs baseline: 1.2551x; 1.2551x over previous
//
#include <hip/hip_runtime.h>

#define VOCABN 256
#define DN 512
#define DSN 2
#define KN 5
#define BN 8
#define LN 8192
#define WN 12                     // window positions per wave (multiple of lcm(2,3,4)=12)
#define NW12 ((LN + WN - 1) / WN) // 683 windows per batch
#define NWIN (BN * NW12)          // 5464 windows total
#define LOUTN (LN / DSN)          // 4096
#define NROWS (KN * VOCABN)       // 1280 G rows
#define ROWB (DN * 2)             // 1024 bytes per bf16 G row
#define KPLANE (VOCABN * ROWB)    // 262144 bytes per k-plane
#define ZOFFB (NROWS * ROWB)      // invalid-tap base: rows 1280+q*256 are zero rows
#define SBIAS_IDX (NROWS + 4 * VOCABN + 1)  // 2305
#define ISP 4                     // split over i: 4 chunks of 128

// Workspace layout (BYTES) — derived:
//   Gp : ISP*NROWS*DN*4 = 10,485,760 @ 0
//   G  : 2305*ROWB      =  2,360,320 @ 10,485,760
//   SW : 2306*4         =      9,224 @ 12,846,080
#define GP_BYTES ((size_t)ISP * NROWS * DN * 4)
#define G_OFF GP_BYTES
#define SW_OFF (G_OFF + (size_t)2305 * ROWB)

__device__ inline unsigned short f2bf(float f) {  // RNE f32->bf16
  unsigned int x = __float_as_uint(f);
  return (unsigned short)((x + 0x7FFFu + ((x >> 16) & 1u)) >> 16);
}

// ---------------- kernel 1: build GEMM partials (round-7/11 verbatim) ----------------
__global__ __launch_bounds__(256) void gbuild_kernel(const float* __restrict__ emb,
                                                     const float* __restrict__ cw,
                                                     float* __restrict__ Gp) {
  const int bx = blockIdx.x;
  const int vt = bx & 3, ot = (bx >> 2) & 7;
  const int kq = bx >> 5;
  const int k = kq % 5, isp = kq / 5;
  const int v0 = vt * 64, o0 = ot * 64;
  const int tid = threadIdx.x;
  const int ox = tid & 15, vx = tid >> 4;
  const int c = tid & 31, rr = tid >> 5;  // stage: i-col 0..31, row-group 0..7
  __shared__ float se[32][68];  // [i][v]
  __shared__ float wt[32][68];  // [i][o]
  float acc[4][4] = {};
  for (int ic = 0; ic < 4; ++ic) {
    const int i0 = isp * 128 + ic * 32;
    __syncthreads();  // protect previous iter's reads
#pragma unroll
    for (int p = 0; p < 8; ++p) {
      const int q = p * 8 + rr;
      se[c][q] = emb[(size_t)(v0 + q) * DN + i0 + c];                  // coalesced rows
      wt[c][q] = cw[((size_t)(o0 + q) * DN + i0 + c) * KN + k];        // strided, L2-hot
    }
    __syncthreads();
#pragma unroll
    for (int i = 0; i < 32; ++i) {
      const float4 a = *(const float4*)&se[i][vx * 4];
      const float4 b = *(const float4*)&wt[i][ox * 4];
      acc[0][0] += a.x * b.x; acc[0][1] += a.x * b.y; acc[0][2] += a.x * b.z; acc[0][3] += a.x * b.w;
      acc[1][0] += a.y * b.x; acc[1][1] += a.y * b.y; acc[1][2] += a.y * b.z; acc[1][3] += a.y * b.w;
      acc[2][0] += a.z * b.x; acc[2][1] += a.z * b.y; acc[2][2] += a.z * b.z; acc[2][3] += a.z * b.w;
      acc[3][0] += a.w * b.x; acc[3][1] += a.w * b.y; acc[3][2] += a.w * b.z; acc[3][3] += a.w * b.w;
    }
  }
#pragma unroll
  for (int vi = 0; vi < 4; ++vi) {
    const int row = k * VOCABN + v0 + vx * 4 + vi;
    float4 f;
    f.x = acc[vi][0];
    f.y = acc[vi][1];
    f.z = acc[vi][2];
    f.w = acc[vi][3];
    *(float4*)(Gp + ((size_t)isp * NROWS + row) * DN + o0 + ox * 4) = f;
  }
}

// ---------------- kernel 2: merged reduce + score table (round-11 verbatim) ----------------
__global__ __launch_bounds__(256) void gswr_kernel(const float* __restrict__ Gp,
                                                   const float* __restrict__ conv_b,
                                                   const float* __restrict__ score_w,
                                                   unsigned int* __restrict__ G32,
                                                   float* __restrict__ SW) {
  const int r = blockIdx.x;
  const int tid = threadIdx.x;
  __shared__ float sred[4];
  if (r >= NROWS && r < NROWS + 5) {  // zero rows
    const int z = NROWS + (r - NROWS) * VOCABN;
    G32[(size_t)z * 256 + tid] = 0u;
    if (tid == 0) SW[z] = 0.f;
    return;
  }
  const float2 sw2 = *(const float2*)(score_w + tid * 2);
  float sdot;
  if (r == NROWS + 5) {  // sbias = conv_b . score_w
    const float2 cb2 = *(const float2*)(conv_b + tid * 2);
    sdot = cb2.x * sw2.x + cb2.y * sw2.y;
  } else {
    float x = 0.f, y = 0.f;
#pragma unroll
    for (int isp = 0; isp < ISP; ++isp) {
      const float2 p = *(const float2*)(Gp + ((size_t)isp * NROWS + r) * DN + tid * 2);
      x += p.x;
      y += p.y;
    }
    G32[(size_t)r * 256 + tid] = (unsigned)f2bf(x) | ((unsigned)f2bf(y) << 16);
    sdot = x * sw2.x + y * sw2.y;
  }
#pragma unroll
  for (int off = 32; off > 0; off >>= 1) sdot += __shfl_xor(sdot, off, 64);
  if ((tid & 63) == 0) sred[tid >> 6] = sdot;
  __syncthreads();
  if (tid == 0) {
    const float v = sred[0] + sred[1] + sred[2] + sred[3];
    if (r == NROWS + 5) SW[SBIAS_IDX] = v;
    else SW[r] = v;
  }
}

// ---------------- kernel 3: fused GBST main — ONE WAVE PER WINDOW ----------------
// 256 thr = 4 independent waves; no LDS, no barriers. 64 lanes x 8 channels (uint4 row
// gathers = one 1024B wave request per tap). Scores/softmax recomputed per lane from
// scalar SW loads; softmax folded into the epilogue (no wm register array).
__global__ __launch_bounds__(256, 3) void gbst_main_kernel(const int* __restrict__ ids,
                                                           const unsigned short* __restrict__ G,
                                                           const float* __restrict__ SW,
                                                           const float* __restrict__ conv_b,
                                                           float* __restrict__ out) {
  const int tid = threadIdx.x;
  const int lane = tid & 63;
  const int wave = __builtin_amdgcn_readfirstlane(tid >> 6);
  const int win = blockIdx.x * 4 + wave;  // NWIN = 1366*4 exactly
  const int b = win / NW12;
  const int w = win - b * NW12;
  const int l0 = w * WN;

  // tap byte-offsets (wave-uniform -> SGPR)
  int joff[WN + 4];
#pragma unroll
  for (int j = 0; j < WN + 4; ++j) {
    const int p = l0 + j - 2;
    const bool v = ((unsigned)p < (unsigned)LN);
    const int a = v ? (b * LN + p) : 0;
    const int id = __builtin_amdgcn_readfirstlane(ids[a]);
    joff[j] = v ? (id * ROWB) : ZOFFB;
  }

  // gathers: uint4 = 8 bf16 channels/lane; scalar base + lane*16 voffset
  const char* Gc = (const char*)G + lane * 16;
  float y[WN][8];
#pragma unroll
  for (int s = 0; s < WN; ++s) {
#pragma unroll
    for (int c = 0; c < 8; ++c) y[s][c] = 0.f;
#pragma unroll
    for (int kk = 0; kk < KN; ++kk) {
      const uint4 g = *(const uint4*)(Gc + (joff[s + kk] + kk * KPLANE));
      y[s][0] += __uint_as_float(g.x << 16);
      y[s][1] += __uint_as_float(g.x & 0xFFFF0000u);
      y[s][2] += __uint_as_float(g.y << 16);
      y[s][3] += __uint_as_float(g.y & 0xFFFF0000u);
      y[s][4] += __uint_as_float(g.z << 16);
      y[s][5] += __uint_as_float(g.z & 0xFFFF0000u);
      y[s][6] += __uint_as_float(g.w << 16);
      y[s][7] += __uint_as_float(g.w & 0xFFFF0000u);
    }
  }
  float bias[8];
  *(float4*)&bias[0] = *(const float4*)(conv_b + lane * 8);
  *(float4*)&bias[4] = *(const float4*)(conv_b + lane * 8 + 4);
#pragma unroll
  for (int s = 0; s < WN; ++s) {
    const bool valid = (l0 + s) < LN;  // wave-uniform
#pragma unroll
    for (int c = 0; c < 8; ++c) y[s][c] = valid ? y[s][c] + bias[c] : 0.f;
  }

  // scores via scalar SW lookups (wave-uniform)
  const float sbias = SW[SBIAS_IDX];
  float t[WN];
#pragma unroll
  for (int s = 0; s < WN; ++s) {
    float tv = sbias;
#pragma unroll
    for (int kk = 0; kk < KN; ++kk) tv += SW[(joff[s + kk] >> 10) + kk * VOCABN];
    t[s] = (l0 + s < LN) ? tv : 0.f;
  }

  // epilogue: softmax on the fly per position; /2 downsample; float4 x2 stores
#pragma unroll
  for (int jo = 0; jo < WN / 2; ++jo) {
    const int orow = (l0 >> 1) + jo;
    if (orow < LOUTN) {  // wave-uniform
      float a[8];
#pragma unroll
      for (int c = 0; c < 8; ++c) a[c] = 0.f;
#pragma unroll
      for (int dl = 0; dl < 2; ++dl) {
        const int ll = 2 * jo + dl;
        const float s1 = t[ll];
        const int j2 = ll & ~1;
        const float s2 = 0.5f * (t[j2] + t[j2 + 1]);
        const int j3 = (ll / 3) * 3;
        const float s3 = (1.f / 3.f) * (t[j3] + t[j3 + 1] + t[j3 + 2]);
        const int j4 = ll & ~3;
        const float s4 = 0.25f * (t[j4] + t[j4 + 1] + t[j4 + 2] + t[j4 + 3]);
        const float mx = fmaxf(fmaxf(s1, s2), fmaxf(s3, s4));
        const float e1 = __expf(s1 - mx), e2 = __expf(s2 - mx);
        const float e3 = __expf(s3 - mx), e4 = __expf(s4 - mx);
        const float inv = 1.f / (e1 + e2 + e3 + e4);
        const float c1 = e1 * inv;
        const float c2 = e2 * inv * 0.5f;
        const float c3 = e3 * inv * (1.f / 3.f);
        const float c4 = e4 * inv * 0.25f;
#pragma unroll
        for (int c = 0; c < 8; ++c) {
          a[c] += c1 * y[ll][c] + c2 * (y[j2][c] + y[j2 + 1][c]) +
                  c3 * (y[j3][c] + y[j3 + 1][c] + y[j3 + 2][c]) +
                  c4 * (y[j4][c] + y[j4 + 1][c] + y[j4 + 2][c] + y[j4 + 3][c]);
        }
      }
      float* orow_p = out + ((size_t)b * LOUTN + orow) * DN + lane * 8;
      float4 o0, o1;
      o0.x = 0.5f * a[0]; o0.y = 0.5f * a[1]; o0.z = 0.5f * a[2]; o0.w = 0.5f * a[3];
      o1.x = 0.5f * a[4]; o1.y = 0.5f * a[5]; o1.z = 0.5f * a[6]; o1.w = 0.5f * a[7];
      *(float4*)orow_p = o0;
      *(float4*)(orow_p + 4) = o1;
    }
  }
}

extern "C" void kernel_launch(void* const* d_in, const int* in_sizes, int n_in,
                              void* d_out, int out_size, void* d_ws, size_t ws_size,
                              hipStream_t stream) {
  const int* ids = (const int*)d_in[0];
  const float* emb = (const float*)d_in[1];
  const float* conv_w = (const float*)d_in[2];
  const float* conv_b = (const float*)d_in[3];
  const float* score_w = (const float*)d_in[4];
  float* out = (float*)d_out;

  char* ws = (char*)d_ws;
  float* Gp = (float*)ws;                               // 10,485,760 B
  unsigned short* G = (unsigned short*)(ws + G_OFF);    // 2,360,320 B @ 10,485,760
  float* SW = (float*)(ws + SW_OFF);                    // 9,224 B @ 12,846,080

  gbuild_kernel<<<dim3(640), dim3(256), 0, stream>>>(emb, conv_w, Gp);
  gswr_kernel<<<dim3(NROWS + 6), dim3(256), 0, stream>>>(Gp, conv_b, score_w,
                                                         (unsigned int*)G, SW);
  gbst_main_kernel<<<dim3(NWIN / 4), dim3(256), 0, stream>>>(ids, G, SW, conv_b, out);
}